// Round 15
// baseline (80.241 us; speedup 1.0000x reference)
//
#include <hip/hip_runtime.h>
#include <math.h>

#define PR 30            // padded rows of h2p
#define PC 32            // padded col stride of h2p; col c <-> px c-1

// 4px x 3kw taps for one co: window = {a.x,a.y,a.z,a.w,b.x,b.y}
__device__ __forceinline__ void tap3(const float4 a, const float2 b,
                                     const float w0, const float w1, const float w2,
                                     float4& acc) {
    acc.x += fabsf(a.x - w0) + fabsf(a.y - w1) + fabsf(a.z - w2);
    acc.y += fabsf(a.y - w0) + fabsf(a.z - w1) + fabsf(a.w - w2);
    acc.z += fabsf(a.z - w0) + fabsf(a.w - w1) + fabsf(b.x - w2);
    acc.w += fabsf(a.w - w0) + fabsf(b.x - w1) + fabsf(b.y - w2);
}

// =========== KA: 1x1 adder(256->64) + PEG depthwise 3x3 + BN1 + ReLU -> h2p ===========
// grid (16 cog, 2 yh, 8 n) = 256 blocks, block 448. Also emits w2t/w3t transposes.
__global__ __launch_bounds__(448) void ka_fused(const float* __restrict__ x,
                                                const float* __restrict__ w1,
                                                const float* __restrict__ wpeg,
                                                const float* __restrict__ w2,
                                                const float* __restrict__ w3,
                                                const float* __restrict__ g1,
                                                const float* __restrict__ b1,
                                                const float* __restrict__ m1,
                                                const float* __restrict__ v1,
                                                float* __restrict__ h2p,
                                                float* __restrict__ w2t,
                                                float* __restrict__ w3t) {
    __shared__ __align__(16) float smem[3072];   // wsA 1024 + h1t 2048 = 12 KB
    float* wsA = smem;            // [256 ci][4 co]
    float* h1t = smem + 1024;     // [4 co][16 rows][32]
    const int tid    = threadIdx.x;
    const int cobase = blockIdx.x * 4;
    const int yh     = blockIdx.y;
    const int n      = blockIdx.z;
    const int co     = tid / 112;
    const int rem    = tid % 112;
    const int row    = rem / 7;
    const int q      = rem % 7;

    // weight transposes for KB (consumed next launch; stream-ordered)
    {
        const int bid3 = blockIdx.x + 16 * (blockIdx.y + 2 * blockIdx.z);
        const int tg = bid3 * 448 + tid;
        if (tg < 36864) {
            int r = tg >> 6, c2 = tg & 63;
            w2t[tg] = w2[(size_t)c2 * 576 + r];             // w2t[r*64+co]
        } else if (tg < 53248) {
            int i = tg - 36864;
            int ci = i >> 8, c2 = i & 255;
            w3t[i] = w3[(size_t)c2 * 64 + ci];              // w3t[ci*256+co]
        }
    }

    for (int idx = tid; idx < 1024; idx += 448) {
        int c2 = idx >> 8, ci = idx & 255;
        wsA[ci * 4 + c2] = w1[(size_t)(cobase + c2) * 256 + ci];
    }
    for (int idx = tid; idx < 512; idx += 448)
        ((float4*)h1t)[idx] = make_float4(0.f, 0.f, 0.f, 0.f);
    __syncthreads();

    const int gy = yh * 14 - 1 + row;
    if (gy >= 0 && gy < 28) {
        float4 acc = {0.f, 0.f, 0.f, 0.f};
        const float* xp = x + (size_t)n * 256 * 784 + gy * 28 + q * 4;
        #pragma unroll 8
        for (int ci = 0; ci < 256; ++ci) {
            float4 u = *(const float4*)(xp + (size_t)ci * 784);
            float w  = wsA[ci * 4 + co];
            acc.x += fabsf(u.x - w); acc.y += fabsf(u.y - w);
            acc.z += fabsf(u.z - w); acc.w += fabsf(u.w - w);
        }
        float* hd = h1t + co * 512 + row * 32 + 1 + q * 4;
        hd[0] = -acc.x; hd[1] = -acc.y; hd[2] = -acc.z; hd[3] = -acc.w;
    }
    __syncthreads();

    if (row < 14) {
        const int c  = cobase + co;
        const int oy = yh * 14 + row;
        const float* wc = wpeg + c * 9;
        const float* hb = h1t + co * 512 + row * 32 + q * 4;
        float4 acc = {0.f, 0.f, 0.f, 0.f};
        #pragma unroll
        for (int kh = 0; kh < 3; ++kh) {
            float4 a  = *(const float4*)(hb + kh * 32);
            float2 bv = *(const float2*)(hb + kh * 32 + 4);
            tap3(a, bv, wc[kh * 3 + 0], wc[kh * 3 + 1], wc[kh * 3 + 2], acc);
        }
        float inv = g1[c] * rsqrtf(v1[c] + 1e-5f);
        float bb  = b1[c] - m1[c] * inv;
        float* op = h2p + ((size_t)(n * 64 + c) * PR + oy + 1) * PC + 1 + q * 4;
        op[0] = fmaxf(-acc.x * inv + bb, 0.f);
        op[1] = fmaxf(-acc.y * inv + bb, 0.f);
        op[2] = fmaxf(-acc.z * inv + bb, 0.f);
        op[3] = fmaxf(-acc.w * inv + bb, 0.f);
    }
    for (int idx = tid; idx < 352; idx += 448) {
        if (idx < 224) {
            int rr = idx >> 4, k = idx & 15;
            int cc = k >> 2, kk = k & 3;
            int col = kk ? 28 + kk : 0;
            h2p[((size_t)(n * 64 + cobase + cc) * PR + yh * 14 + 1 + rr) * PC + col] = 0.f;
        } else {
            int j = idx - 224;
            int cc = j >> 5, col = j & 31;
            int prow = yh ? 29 : 0;
            h2p[((size_t)(n * 64 + cobase + cc) * PR + prow) * PC + col] = 0.f;
        }
    }
}

// =========== KB: 3x3 adder(64->64)+BN2+ReLU + 1x1 adder(64->256)+BN3+res+ReLU ===========
// grid (2 half, 28 Y, 8 n) = 448 blocks, block 512 = 8cic x 16colane x 4q.
// Block computes 16 px (half*12 .. +15; px 12..15 duplicated across halves) of one row,
// ALL 64 h3 channels in LDS, then the 256-co 1x1 from LDS. 67 KB LDS, phase-unioned.
__global__ __launch_bounds__(512) void kb_fused(const float* __restrict__ h2p,
                                                const float* __restrict__ w2t,
                                                const float* __restrict__ w3t,
                                                const float* __restrict__ x,
                                                const float* __restrict__ g2,
                                                const float* __restrict__ b2,
                                                const float* __restrict__ m2,
                                                const float* __restrict__ v2,
                                                const float* __restrict__ g3,
                                                const float* __restrict__ b3,
                                                const float* __restrict__ m3,
                                                const float* __restrict__ v3,
                                                float* __restrict__ out) {
    __shared__ __align__(16) float smem[17216];  // 67.25 KB
    float*  h3t  = smem;                  // [64 ch][20]               (A-end .. B)
    float*  h2t  = smem + 1280;           // [64 ci][3 r][32]          (A only)
    float*  wck  = smem + 7424;           // [16 ci_l][9 tap][68]      (A only, per chunk)
    float4* pl4  = (float4*)(smem + 1280);// 2048 f4 partials (over dead h2t/wck)
    float*  w3ch = smem + 1280;           // [32 ci][260] (B only, 2 chunks)
    const int tid    = threadIdx.x;
    const int half   = blockIdx.x;        // 0..1 -> px base half*12
    const int Y      = blockIdx.y;        // output row
    const int n      = blockIdx.z;
    const int cic    = tid >> 6;          // 0..7
    const int colane = (tid >> 2) & 15;   // co-quad colane*4
    const int q      = tid & 3;           // px-quad: px = half*12 + q*4
    const int pxb    = half * 12;

    // stage h2t: rows Y..Y+2, all 64 ci, full 32 cols (float4, coalesced, conflict-free)
    for (int iq = tid; iq < 1536; iq += 512) {
        int ci = iq / 24, r2 = iq % 24;
        int r = r2 >> 3, c4 = r2 & 7;
        *(float4*)(h2t + ci * 96 + r * 32 + c4 * 4) =
            *(const float4*)(h2p + ((size_t)(n * 64 + ci) * PR + Y + r) * PC + c4 * 4);
    }
    __syncthreads();

    // ---- phase A: 3x3 adder, 4 chunks of 16 ci; thread does ci = ch*16 + i2*8 + cic ----
    float4 acc0 = {0,0,0,0}, acc1 = acc0, acc2 = acc0, acc3 = acc0;
    for (int ch = 0; ch < 4; ++ch) {
        for (int iq = tid; iq < 2304; iq += 512) {       // stage w2t chunk: f4, no conflicts
            int r_l = iq >> 4, coq = iq & 15;
            *(float4*)(wck + r_l * 68 + coq * 4) =
                *(const float4*)(w2t + (size_t)(ch * 144 + r_l) * 64 + coq * 4);
        }
        __syncthreads();
        #pragma unroll
        for (int i2 = 0; i2 < 2; ++i2) {
            const int ci_l = i2 * 8 + cic;               // 0..15
            const int ci   = ch * 16 + ci_l;
            const float* hb = h2t + ci * 96 + pxb + q * 4;
            const float* wb = wck + ci_l * 612 + colane * 4;
            #pragma unroll
            for (int kh = 0; kh < 3; ++kh) {
                float4 a  = *(const float4*)(hb + kh * 32);
                float2 bv = *(const float2*)(hb + kh * 32 + 4);
                float4 W0 = *(const float4*)(wb + (kh * 3 + 0) * 68);
                float4 W1 = *(const float4*)(wb + (kh * 3 + 1) * 68);
                float4 W2 = *(const float4*)(wb + (kh * 3 + 2) * 68);
                tap3(a, bv, W0.x, W1.x, W2.x, acc0);
                tap3(a, bv, W0.y, W1.y, W2.y, acc1);
                tap3(a, bv, W0.z, W1.z, W2.z, acc2);
                tap3(a, bv, W0.w, W1.w, W2.w, acc3);
            }
        }
        __syncthreads();
    }
    // partials (conflict-free writes), reduce over cic, BN2+ReLU -> h3t
    pl4[tid +    0] = acc0;
    pl4[tid +  512] = acc1;
    pl4[tid + 1024] = acc2;
    pl4[tid + 1536] = acc3;
    __syncthreads();
    if (tid < 256) {
        const int rl = tid >> 4;          // colane
        const int rq = (tid >> 2) & 3;    // q
        const int j  = tid & 3;           // co within quad
        float4 s = pl4[rl * 4 + rq + j * 512];
        #pragma unroll
        for (int c = 1; c < 8; ++c) {
            float4 t = pl4[c * 64 + rl * 4 + rq + j * 512];
            s.x += t.x; s.y += t.y; s.z += t.z; s.w += t.w;
        }
        const int co = rl * 4 + j;
        float inv = g2[co] * rsqrtf(v2[co] + 1e-5f);
        float bb  = b2[co] - m2[co] * inv;
        float4 o;
        o.x = fmaxf(-s.x * inv + bb, 0.f);
        o.y = fmaxf(-s.y * inv + bb, 0.f);
        o.z = fmaxf(-s.z * inv + bb, 0.f);
        o.w = fmaxf(-s.w * inv + bb, 0.f);
        *(float4*)(h3t + co * 20 + rq * 4) = o;
    }
    __syncthreads();

    // ---- phase B: 1x1 adder 64->256 (+BN3+res+ReLU), 2 ci-chunks of 32 ----
    const int bl = tid >> 2;              // 0..63 co-quad (active tid<256)
    const int bq = tid & 3;               // px-quad
    float4 a0 = {0,0,0,0}, a1 = a0, a2 = a0, a3 = a0;
    for (int ch2 = 0; ch2 < 2; ++ch2) {
        for (int iq = tid; iq < 2048; iq += 512) {       // stage w3t chunk: f4, no conflicts
            int ci_l = iq >> 6, coq = iq & 63;
            *(float4*)(w3ch + ci_l * 260 + coq * 4) =
                *(const float4*)(w3t + (size_t)(ch2 * 32 + ci_l) * 256 + coq * 4);
        }
        __syncthreads();
        if (tid < 256) {
            const float* hb = h3t + bq * 4;
            const float* wb = w3ch + bl * 4;
            #pragma unroll 8
            for (int ci_l = 0; ci_l < 32; ++ci_l) {
                float4 h = *(const float4*)(hb + (ch2 * 32 + ci_l) * 20);
                float4 w = *(const float4*)(wb + ci_l * 260);
                a0.x += fabsf(h.x - w.x); a0.y += fabsf(h.y - w.x); a0.z += fabsf(h.z - w.x); a0.w += fabsf(h.w - w.x);
                a1.x += fabsf(h.x - w.y); a1.y += fabsf(h.y - w.y); a1.z += fabsf(h.z - w.y); a1.w += fabsf(h.w - w.y);
                a2.x += fabsf(h.x - w.z); a2.y += fabsf(h.y - w.z); a2.z += fabsf(h.z - w.z); a2.w += fabsf(h.w - w.z);
                a3.x += fabsf(h.x - w.w); a3.y += fabsf(h.y - w.w); a3.z += fabsf(h.z - w.w); a3.w += fabsf(h.w - w.w);
            }
        }
        __syncthreads();
    }
    if (tid < 256) {
        float4 accs[4] = {a0, a1, a2, a3};
        #pragma unroll
        for (int j = 0; j < 4; ++j) {
            const int co = bl * 4 + j;
            float inv = g3[co] * rsqrtf(v3[co] + 1e-5f);
            float bb  = b3[co] - m3[co] * inv;
            size_t obase = ((size_t)n * 256 + co) * 784 + Y * 28 + pxb + bq * 4;
            float4 r = *(const float4*)(x + obase);
            float4 o;
            o.x = fmaxf(-accs[j].x * inv + bb + r.x, 0.f);
            o.y = fmaxf(-accs[j].y * inv + bb + r.y, 0.f);
            o.z = fmaxf(-accs[j].z * inv + bb + r.z, 0.f);
            o.w = fmaxf(-accs[j].w * inv + bb + r.w, 0.f);
            *(float4*)(out + obase) = o;
        }
    }
}

extern "C" void kernel_launch(void* const* d_in, const int* in_sizes, int n_in,
                              void* d_out, int out_size, void* d_ws, size_t ws_size,
                              hipStream_t stream) {
    const float* x  = (const float*)d_in[0];
    const float* w1 = (const float*)d_in[1];
    const float* wp = (const float*)d_in[2];
    const float* w2 = (const float*)d_in[3];
    const float* w3 = (const float*)d_in[4];
    const float* g1 = (const float*)d_in[5];
    const float* b1 = (const float*)d_in[6];
    const float* m1 = (const float*)d_in[7];
    const float* v1 = (const float*)d_in[8];
    const float* g2 = (const float*)d_in[9];
    const float* b2 = (const float*)d_in[10];
    const float* m2 = (const float*)d_in[11];
    const float* v2 = (const float*)d_in[12];
    const float* g3 = (const float*)d_in[13];
    const float* b3 = (const float*)d_in[14];
    const float* m3 = (const float*)d_in[15];
    const float* v3 = (const float*)d_in[16];
    float* out = (float*)d_out;

    float* wsf = (float*)d_ws;
    float* h2p = wsf;                 // 491520 floats
    float* w2t = wsf + 491520;        // 36864 floats [576 r][64 co]
    float* w3t = wsf + 528384;        // 16384 floats [64 ci][256 co]

    ka_fused<<<dim3(16, 2, 8), 448, 0, stream>>>(x, w1, wp, w2, w3,
                                                 g1, b1, m1, v1, h2p, w2t, w3t);
    kb_fused<<<dim3(2, 28, 8), 512, 0, stream>>>(h2p, w2t, w3t, x,
                                                 g2, b2, m2, v2, g3, b3, m3, v3, out);
}

// Round 16
// 71.150 us; speedup vs baseline: 1.1278x; 1.1278x over previous
//
#include <hip/hip_runtime.h>
#include <math.h>

#define PR 30            // padded rows of h2p
#define PC 32            // padded col stride of h2p; col c <-> px c-1

// 4px x 3kw taps for one co: window = {a.x,a.y,a.z,a.w,b.x,b.y}
__device__ __forceinline__ void tap3(const float4 a, const float2 b,
                                     const float w0, const float w1, const float w2,
                                     float4& acc) {
    acc.x += fabsf(a.x - w0) + fabsf(a.y - w1) + fabsf(a.z - w2);
    acc.y += fabsf(a.y - w0) + fabsf(a.z - w1) + fabsf(a.w - w2);
    acc.z += fabsf(a.z - w0) + fabsf(a.w - w1) + fabsf(b.x - w2);
    acc.w += fabsf(a.w - w0) + fabsf(b.x - w1) + fabsf(b.y - w2);
}

// =========== KA: 1x1 adder(256->64) + PEG depthwise 3x3 + BN1 + ReLU -> h2p ===========
// grid (16 cog, 2 yh, 8 n) = 256 blocks, block 448. Also emits w2t/w3t transposes.
__global__ __launch_bounds__(448) void ka_fused(const float* __restrict__ x,
                                                const float* __restrict__ w1,
                                                const float* __restrict__ wpeg,
                                                const float* __restrict__ w2,
                                                const float* __restrict__ w3,
                                                const float* __restrict__ g1,
                                                const float* __restrict__ b1,
                                                const float* __restrict__ m1,
                                                const float* __restrict__ v1,
                                                float* __restrict__ h2p,
                                                float* __restrict__ w2t,
                                                float* __restrict__ w3t) {
    __shared__ __align__(16) float smem[3072];   // wsA 1024 + h1t 2048 = 12 KB
    float* wsA = smem;            // [256 ci][4 co]
    float* h1t = smem + 1024;     // [4 co][16 rows][32]
    const int tid    = threadIdx.x;
    const int cobase = blockIdx.x * 4;
    const int yh     = blockIdx.y;
    const int n      = blockIdx.z;
    const int co     = tid / 112;
    const int rem    = tid % 112;
    const int row    = rem / 7;
    const int q      = rem % 7;

    // weight transposes for KB (consumed next launch; stream-ordered)
    {
        const int bid3 = blockIdx.x + 16 * (blockIdx.y + 2 * blockIdx.z);
        const int tg = bid3 * 448 + tid;
        if (tg < 36864) {
            int r = tg >> 6, c2 = tg & 63;
            w2t[tg] = w2[(size_t)c2 * 576 + r];             // w2t[r*64+co]
        } else if (tg < 53248) {
            int i = tg - 36864;
            int ci = i >> 8, c2 = i & 255;
            w3t[i] = w3[(size_t)c2 * 64 + ci];              // w3t[ci*256+co]
        }
    }

    for (int idx = tid; idx < 1024; idx += 448) {
        int c2 = idx >> 8, ci = idx & 255;
        wsA[ci * 4 + c2] = w1[(size_t)(cobase + c2) * 256 + ci];
    }
    for (int idx = tid; idx < 512; idx += 448)
        ((float4*)h1t)[idx] = make_float4(0.f, 0.f, 0.f, 0.f);
    __syncthreads();

    const int gy = yh * 14 - 1 + row;
    if (gy >= 0 && gy < 28) {
        float4 acc = {0.f, 0.f, 0.f, 0.f};
        const float* xp = x + (size_t)n * 256 * 784 + gy * 28 + q * 4;
        #pragma unroll 8
        for (int ci = 0; ci < 256; ++ci) {
            float4 u = *(const float4*)(xp + (size_t)ci * 784);
            float w  = wsA[ci * 4 + co];
            acc.x += fabsf(u.x - w); acc.y += fabsf(u.y - w);
            acc.z += fabsf(u.z - w); acc.w += fabsf(u.w - w);
        }
        float* hd = h1t + co * 512 + row * 32 + 1 + q * 4;
        hd[0] = -acc.x; hd[1] = -acc.y; hd[2] = -acc.z; hd[3] = -acc.w;
    }
    __syncthreads();

    if (row < 14) {
        const int c  = cobase + co;
        const int oy = yh * 14 + row;
        const float* wc = wpeg + c * 9;
        const float* hb = h1t + co * 512 + row * 32 + q * 4;
        float4 acc = {0.f, 0.f, 0.f, 0.f};
        #pragma unroll
        for (int kh = 0; kh < 3; ++kh) {
            float4 a  = *(const float4*)(hb + kh * 32);
            float2 bv = *(const float2*)(hb + kh * 32 + 4);
            tap3(a, bv, wc[kh * 3 + 0], wc[kh * 3 + 1], wc[kh * 3 + 2], acc);
        }
        float inv = g1[c] * rsqrtf(v1[c] + 1e-5f);
        float bb  = b1[c] - m1[c] * inv;
        float* op = h2p + ((size_t)(n * 64 + c) * PR + oy + 1) * PC + 1 + q * 4;
        op[0] = fmaxf(-acc.x * inv + bb, 0.f);
        op[1] = fmaxf(-acc.y * inv + bb, 0.f);
        op[2] = fmaxf(-acc.z * inv + bb, 0.f);
        op[3] = fmaxf(-acc.w * inv + bb, 0.f);
    }
    for (int idx = tid; idx < 352; idx += 448) {
        if (idx < 224) {
            int rr = idx >> 4, k = idx & 15;
            int cc = k >> 2, kk = k & 3;
            int col = kk ? 28 + kk : 0;
            h2p[((size_t)(n * 64 + cobase + cc) * PR + yh * 14 + 1 + rr) * PC + col] = 0.f;
        } else {
            int j = idx - 224;
            int cc = j >> 5, col = j & 31;
            int prow = yh ? 29 : 0;
            h2p[((size_t)(n * 64 + cobase + cc) * PR + prow) * PC + col] = 0.f;
        }
    }
}

// shfl-xor f4 add helper (64-wide wave)
__device__ __forceinline__ void red4(float4& v, int mask) {
    v.x += __shfl_xor(v.x, mask, 64);
    v.y += __shfl_xor(v.y, mask, 64);
    v.z += __shfl_xor(v.z, mask, 64);
    v.w += __shfl_xor(v.w, mask, 64);
}

// =========== KB: 3x3 adder(64->64)+BN2+ReLU + 1x1 adder(64->256)+BN3+res+ReLU ===========
// grid (2 half, 28 Y, 8 n) = 448 blocks, block 512.
// Weights read directly from global w2t/w3t (L2-resident, broadcast-coalesced).
// ci-reduction via in-wave shfl (cic = tid&7). LDS: h2t (padded 100) + h3t = 30 KB. 2 barriers.
__global__ __launch_bounds__(512) void kb_fused(const float* __restrict__ h2p,
                                                const float* __restrict__ w2t,
                                                const float* __restrict__ w3t,
                                                const float* __restrict__ x,
                                                const float* __restrict__ g2,
                                                const float* __restrict__ b2,
                                                const float* __restrict__ m2,
                                                const float* __restrict__ v2,
                                                const float* __restrict__ g3,
                                                const float* __restrict__ b3,
                                                const float* __restrict__ m3,
                                                const float* __restrict__ v3,
                                                float* __restrict__ out) {
    __shared__ __align__(16) float h2t[6400];    // [64 ci][100] (3 rows x 32 + 4 pad)
    __shared__ __align__(16) float h3t[1280];    // [64 ch][20]
    const int tid  = threadIdx.x;
    const int half = blockIdx.x;          // px base = half*12
    const int Y    = blockIdx.y;          // output row
    const int n    = blockIdx.z;
    const int cic    = tid & 7;           // in-wave ci-split (bits 0..2)
    const int q      = (tid >> 3) & 3;    // px-quad
    const int colane = tid >> 5;          // 0..15 co-quad
    const int pxb    = half * 12;

    // stage h2t: rows Y..Y+2, 64 ci, full 32 cols (f4, coalesced; row stride 100 kills bank aliasing)
    for (int iq = tid; iq < 1536; iq += 512) {
        int ci = iq / 24, r2 = iq % 24;
        int r = r2 >> 3, c4 = r2 & 7;
        *(float4*)(h2t + ci * 100 + r * 32 + c4 * 4) =
            *(const float4*)(h2p + ((size_t)(n * 64 + ci) * PR + Y + r) * PC + c4 * 4);
    }
    __syncthreads();

    // ---- phase A: 3x3 adder; thread: 8 ci x 9 taps x 4 co x 4 px; weights from global ----
    float4 acc0 = {0,0,0,0}, acc1 = acc0, acc2 = acc0, acc3 = acc0;
    #pragma unroll 2
    for (int ci8 = 0; ci8 < 8; ++ci8) {
        const int ci = ci8 * 8 + cic;
        const float* hb = h2t + ci * 100 + pxb + q * 4;
        const float* wr = w2t + (size_t)ci * 576 + colane * 4;   // (ci*9+tap)*64 + co
        #pragma unroll
        for (int kh = 0; kh < 3; ++kh) {
            float4 a  = *(const float4*)(hb + kh * 32);
            float2 bv = *(const float2*)(hb + kh * 32 + 4);
            float4 W0 = *(const float4*)(wr + (kh * 3 + 0) * 64);
            float4 W1 = *(const float4*)(wr + (kh * 3 + 1) * 64);
            float4 W2 = *(const float4*)(wr + (kh * 3 + 2) * 64);
            tap3(a, bv, W0.x, W1.x, W2.x, acc0);
            tap3(a, bv, W0.y, W1.y, W2.y, acc1);
            tap3(a, bv, W0.z, W1.z, W2.z, acc2);
            tap3(a, bv, W0.w, W1.w, W2.w, acc3);
        }
    }
    // in-wave 8-way reduce over cic (tid bits 0..2)
    red4(acc0, 1); red4(acc0, 2); red4(acc0, 4);
    red4(acc1, 1); red4(acc1, 2); red4(acc1, 4);
    red4(acc2, 1); red4(acc2, 2); red4(acc2, 4);
    red4(acc3, 1); red4(acc3, 2); red4(acc3, 4);
    // BN2 + ReLU -> h3t (lanes cic 0..3 each handle one co of the quad)
    if (cic < 4) {
        float4 s = (cic == 0) ? acc0 : (cic == 1) ? acc1 : (cic == 2) ? acc2 : acc3;
        const int co = colane * 4 + cic;
        float inv = g2[co] * rsqrtf(v2[co] + 1e-5f);
        float bb  = b2[co] - m2[co] * inv;
        float4 o;
        o.x = fmaxf(-s.x * inv + bb, 0.f);
        o.y = fmaxf(-s.y * inv + bb, 0.f);
        o.z = fmaxf(-s.z * inv + bb, 0.f);
        o.w = fmaxf(-s.w * inv + bb, 0.f);
        *(float4*)(h3t + co * 20 + q * 4) = o;
    }
    __syncthreads();

    // ---- phase B: 1x1 adder 64->256 + BN3 + res + ReLU; thread: 32 ci x 4 co x 4 px ----
    {
        const int bl  = tid >> 3;         // 0..63 co-quad
        const int cih = (tid >> 2) & 1;   // ci half (in-wave bit 2)
        const int bq  = tid & 3;          // px-quad
        float4 a0 = {0,0,0,0}, a1 = a0, a2 = a0, a3 = a0;
        const float* hb = h3t + cih * 32 * 20 + bq * 4;
        const float* wb = w3t + (size_t)(cih * 32) * 256 + bl * 4;
        #pragma unroll 8
        for (int ci_l = 0; ci_l < 32; ++ci_l) {
            float4 h = *(const float4*)(hb + ci_l * 20);
            float4 w = *(const float4*)(wb + ci_l * 256);
            a0.x += fabsf(h.x - w.x); a0.y += fabsf(h.y - w.x); a0.z += fabsf(h.z - w.x); a0.w += fabsf(h.w - w.x);
            a1.x += fabsf(h.x - w.y); a1.y += fabsf(h.y - w.y); a1.z += fabsf(h.z - w.y); a1.w += fabsf(h.w - w.y);
            a2.x += fabsf(h.x - w.z); a2.y += fabsf(h.y - w.z); a2.z += fabsf(h.z - w.z); a2.w += fabsf(h.w - w.z);
            a3.x += fabsf(h.x - w.w); a3.y += fabsf(h.y - w.w); a3.z += fabsf(h.z - w.w); a3.w += fabsf(h.w - w.w);
        }
        // 2-way reduce over cih (tid bit 2)
        red4(a0, 4); red4(a1, 4); red4(a2, 4); red4(a3, 4);
        if (cih == 0) {
            float4 accs0 = a0, accs1 = a1, accs2 = a2, accs3 = a3;
            #pragma unroll
            for (int j = 0; j < 4; ++j) {
                float4 s = (j == 0) ? accs0 : (j == 1) ? accs1 : (j == 2) ? accs2 : accs3;
                const int co = bl * 4 + j;
                float inv = g3[co] * rsqrtf(v3[co] + 1e-5f);
                float bb  = b3[co] - m3[co] * inv;
                size_t obase = ((size_t)n * 256 + co) * 784 + Y * 28 + pxb + bq * 4;
                float4 r = *(const float4*)(x + obase);
                float4 o;
                o.x = fmaxf(-s.x * inv + bb + r.x, 0.f);
                o.y = fmaxf(-s.y * inv + bb + r.y, 0.f);
                o.z = fmaxf(-s.z * inv + bb + r.z, 0.f);
                o.w = fmaxf(-s.w * inv + bb + r.w, 0.f);
                *(float4*)(out + obase) = o;
            }
        }
    }
}

extern "C" void kernel_launch(void* const* d_in, const int* in_sizes, int n_in,
                              void* d_out, int out_size, void* d_ws, size_t ws_size,
                              hipStream_t stream) {
    const float* x  = (const float*)d_in[0];
    const float* w1 = (const float*)d_in[1];
    const float* wp = (const float*)d_in[2];
    const float* w2 = (const float*)d_in[3];
    const float* w3 = (const float*)d_in[4];
    const float* g1 = (const float*)d_in[5];
    const float* b1 = (const float*)d_in[6];
    const float* m1 = (const float*)d_in[7];
    const float* v1 = (const float*)d_in[8];
    const float* g2 = (const float*)d_in[9];
    const float* b2 = (const float*)d_in[10];
    const float* m2 = (const float*)d_in[11];
    const float* v2 = (const float*)d_in[12];
    const float* g3 = (const float*)d_in[13];
    const float* b3 = (const float*)d_in[14];
    const float* m3 = (const float*)d_in[15];
    const float* v3 = (const float*)d_in[16];
    float* out = (float*)d_out;

    float* wsf = (float*)d_ws;
    float* h2p = wsf;                 // 491520 floats
    float* w2t = wsf + 491520;        // 36864 floats [576 r][64 co]
    float* w3t = wsf + 528384;        // 16384 floats [64 ci][256 co]

    ka_fused<<<dim3(16, 2, 8), 448, 0, stream>>>(x, w1, wp, w2, w3,
                                                 g1, b1, m1, v1, h2p, w2t, w3t);
    kb_fused<<<dim3(2, 28, 8), 512, 0, stream>>>(h2p, w2t, w3t, x,
                                                 g2, b2, m2, v2, g3, b3, m3, v3, out);
}

// Round 17
// 65.137 us; speedup vs baseline: 1.2319x; 1.0923x over previous
//
#include <hip/hip_runtime.h>
#include <math.h>

#define PR 30            // padded rows of h2p
#define PC 32            // padded col stride of h2p

// 4px x 3kw taps for one co: window = {a.x,a.y,a.z,a.w,b.x,b.y}
__device__ __forceinline__ void tap3(const float4 a, const float2 b,
                                     const float w0, const float w1, const float w2,
                                     float4& acc) {
    acc.x += fabsf(a.x - w0) + fabsf(a.y - w1) + fabsf(a.z - w2);
    acc.y += fabsf(a.y - w0) + fabsf(a.z - w1) + fabsf(a.w - w2);
    acc.z += fabsf(a.z - w0) + fabsf(a.w - w1) + fabsf(b.x - w2);
    acc.w += fabsf(a.w - w0) + fabsf(b.x - w1) + fabsf(b.y - w2);
}

// =========== KA: 1x1 adder(256->64) + PEG depthwise 3x3 + BN1 + ReLU -> h2p ===========
// grid (16 cog, 2 yh, 8 n) = 256 blocks, block 448. Also emits w2t transpose.
__global__ __launch_bounds__(448) void ka_fused(const float* __restrict__ x,
                                                const float* __restrict__ w1,
                                                const float* __restrict__ wpeg,
                                                const float* __restrict__ w2,
                                                const float* __restrict__ g1,
                                                const float* __restrict__ b1,
                                                const float* __restrict__ m1,
                                                const float* __restrict__ v1,
                                                float* __restrict__ h2p,
                                                float* __restrict__ w2t) {
    __shared__ __align__(16) float smem[3072];   // wsA 1024 + h1t 2048 = 12 KB
    float* wsA = smem;            // [256 ci][4 co]
    float* h1t = smem + 1024;     // [4 co][16 rows][32]
    const int tid    = threadIdx.x;
    const int cobase = blockIdx.x * 4;
    const int yh     = blockIdx.y;
    const int n      = blockIdx.z;
    const int co     = tid / 112;
    const int rem    = tid % 112;
    const int row    = rem / 7;
    const int q      = rem % 7;

    // w2 transpose for k3 (consumed next launch; stream-ordered): w2t[r*64+co]
    {
        const int bid3 = blockIdx.x + 16 * (blockIdx.y + 2 * blockIdx.z);
        const int tg = bid3 * 448 + tid;
        if (tg < 36864) {
            int r = tg >> 6, c2 = tg & 63;
            w2t[tg] = w2[(size_t)c2 * 576 + r];
        }
    }

    for (int idx = tid; idx < 1024; idx += 448) {
        int c2 = idx >> 8, ci = idx & 255;
        wsA[ci * 4 + c2] = w1[(size_t)(cobase + c2) * 256 + ci];
    }
    for (int idx = tid; idx < 512; idx += 448)
        ((float4*)h1t)[idx] = make_float4(0.f, 0.f, 0.f, 0.f);
    __syncthreads();

    const int gy = yh * 14 - 1 + row;
    if (gy >= 0 && gy < 28) {
        float4 acc = {0.f, 0.f, 0.f, 0.f};
        const float* xp = x + (size_t)n * 256 * 784 + gy * 28 + q * 4;
        #pragma unroll 8
        for (int ci = 0; ci < 256; ++ci) {
            float4 u = *(const float4*)(xp + (size_t)ci * 784);
            float w  = wsA[ci * 4 + co];
            acc.x += fabsf(u.x - w); acc.y += fabsf(u.y - w);
            acc.z += fabsf(u.z - w); acc.w += fabsf(u.w - w);
        }
        float* hd = h1t + co * 512 + row * 32 + 1 + q * 4;
        hd[0] = -acc.x; hd[1] = -acc.y; hd[2] = -acc.z; hd[3] = -acc.w;
    }
    __syncthreads();

    if (row < 14) {
        const int c  = cobase + co;
        const int oy = yh * 14 + row;
        const float* wc = wpeg + c * 9;
        const float* hb = h1t + co * 512 + row * 32 + q * 4;
        float4 acc = {0.f, 0.f, 0.f, 0.f};
        #pragma unroll
        for (int kh = 0; kh < 3; ++kh) {
            float4 a  = *(const float4*)(hb + kh * 32);
            float2 bv = *(const float2*)(hb + kh * 32 + 4);
            tap3(a, bv, wc[kh * 3 + 0], wc[kh * 3 + 1], wc[kh * 3 + 2], acc);
        }
        float inv = g1[c] * rsqrtf(v1[c] + 1e-5f);
        float bb  = b1[c] - m1[c] * inv;
        float* op = h2p + ((size_t)(n * 64 + c) * PR + oy + 1) * PC + 1 + q * 4;
        op[0] = fmaxf(-acc.x * inv + bb, 0.f);
        op[1] = fmaxf(-acc.y * inv + bb, 0.f);
        op[2] = fmaxf(-acc.z * inv + bb, 0.f);
        op[3] = fmaxf(-acc.w * inv + bb, 0.f);
    }
    for (int idx = tid; idx < 352; idx += 448) {
        if (idx < 224) {
            int rr = idx >> 4, k = idx & 15;
            int cc = k >> 2, kk = k & 3;
            int col = kk ? 28 + kk : 0;
            h2p[((size_t)(n * 64 + cobase + cc) * PR + yh * 14 + 1 + rr) * PC + col] = 0.f;
        } else {
            int j = idx - 224;
            int cc = j >> 5, col = j & 31;
            int prow = yh ? 29 : 0;
            h2p[((size_t)(n * 64 + cobase + cc) * PR + prow) * PC + col] = 0.f;
        }
    }
}

// =========== K3: 3x3 adder 64->64 + BN2 + ReLU -> h3 ===========
// grid (8 co-oct, 14 row-pairs, 8 n) = 896 blocks, block 256 = 4 waves.
// Lane = pixel (2 rows x 32 cols); wave = (cq co-quad, cic ci-half).
// Window: stride-1 scalar LDS (2-way = free). Weights: wave-uniform LDS broadcast (free).
__global__ __launch_bounds__(256) void k3_conv(const float* __restrict__ h2p,
                                               const float* __restrict__ w2t,
                                               const float* __restrict__ g2,
                                               const float* __restrict__ b2,
                                               const float* __restrict__ m2,
                                               const float* __restrict__ v2,
                                               float* __restrict__ h3) {
    __shared__ __align__(16) float wt[4608];     // [576 tap][8 co]
    __shared__ __align__(16) float h2t[8200];    // [64 ci][4 rows][32] (+8 overrun pad)
    __shared__ __align__(16) float pl[512];      // 128 f4 partials
    const int tid  = threadIdx.x;
    const int lane = tid & 63;
    const int wv   = tid >> 6;        // 0..3
    const int cq   = wv & 1;          // co-quad within oct
    const int cic  = wv >> 1;         // ci-half
    const int col  = lane & 31;
    const int rowl = lane >> 5;       // 0..1
    const int cobase = blockIdx.x * 8;
    const int Y0     = blockIdx.y * 2;
    const int n      = blockIdx.z;
    const int Y      = Y0 + rowl;

    // stage h2t: padded rows Y0..Y0+3, 64 ci (f4, coalesced)
    #pragma unroll
    for (int i = 0; i < 8; ++i) {
        int idx = i * 256 + tid;          // < 2048
        int ci = idx >> 5, r2 = idx & 31, r = r2 >> 3, c4 = r2 & 7;
        *(float4*)(h2t + ci * 128 + r * 32 + c4 * 4) =
            *(const float4*)(h2p + ((size_t)(n * 64 + ci) * PR + Y0 + r) * PC + c4 * 4);
    }
    // stage wt: 576 taps x 8 cos of this oct
    #pragma unroll
    for (int i = 0; i < 5; ++i) {
        int idx = i * 256 + tid;
        if (idx < 1152) {
            int tap = idx >> 1, c8 = (idx & 1) * 4;
            *(float4*)(wt + tap * 8 + c8) =
                *(const float4*)(w2t + (size_t)tap * 64 + cobase + c8);
        }
    }
    __syncthreads();

    float4 acc = {0.f, 0.f, 0.f, 0.f};
    const float* hb = h2t + rowl * 32 + col;
    const float* wb = wt + cq * 4;
    #pragma unroll 4
    for (int i = 0; i < 32; ++i) {
        const int ci = cic * 32 + i;
        const float* hr = hb + ci * 128;
        const float* wr = wb + ci * 72;
        #pragma unroll
        for (int kh = 0; kh < 3; ++kh) {
            float x0 = hr[kh * 32 + 0];
            float x1 = hr[kh * 32 + 1];
            float x2 = hr[kh * 32 + 2];
            float4 w0  = *(const float4*)(wr + (kh * 3 + 0) * 8);
            float4 w1v = *(const float4*)(wr + (kh * 3 + 1) * 8);
            float4 w2v = *(const float4*)(wr + (kh * 3 + 2) * 8);
            acc.x += fabsf(x0 - w0.x) + fabsf(x1 - w1v.x) + fabsf(x2 - w2v.x);
            acc.y += fabsf(x0 - w0.y) + fabsf(x1 - w1v.y) + fabsf(x2 - w2v.y);
            acc.z += fabsf(x0 - w0.z) + fabsf(x1 - w1v.z) + fabsf(x2 - w2v.z);
            acc.w += fabsf(x0 - w0.w) + fabsf(x1 - w1v.w) + fabsf(x2 - w2v.w);
        }
    }
    // 2-way cross-wave ci reduce
    __syncthreads();                      // all h2t/wt reads done (pl separate, but cheap safety)
    if (cic == 1) ((float4*)pl)[cq * 64 + lane] = acc;
    __syncthreads();
    if (cic == 0 && col < 28) {
        float4 t = ((float4*)pl)[cq * 64 + lane];
        acc.x += t.x; acc.y += t.y; acc.z += t.z; acc.w += t.w;
        float s[4] = {acc.x, acc.y, acc.z, acc.w};
        float* o = h3 + ((size_t)(n * 64 + cobase + cq * 4)) * 784 + Y * 28 + col;
        #pragma unroll
        for (int j = 0; j < 4; ++j) {
            const int co = cobase + cq * 4 + j;
            float inv = g2[co] * rsqrtf(v2[co] + 1e-5f);
            float bb  = b2[co] - m2[co] * inv;
            o[j * 784] = fmaxf(-s[j] * inv + bb, 0.f);
        }
    }
}

// =========== K6: 1x1 adder 64->256 + BN3 + residual + ReLU (R12 proven) ===========
// grid (112, 8): blockIdx.x = n*14 + pxtile(56px). block 448 = 8cog x 14pxg x 4cic.
__global__ __launch_bounds__(448) void k6_adder1x1_bn_res_relu(const float* __restrict__ h3,
                                                               const float* __restrict__ w3,
                                                               const float* __restrict__ x,
                                                               const float* __restrict__ g3,
                                                               const float* __restrict__ b3,
                                                               const float* __restrict__ m3,
                                                               const float* __restrict__ v3,
                                                               float* __restrict__ out) {
    __shared__ __align__(16) float smem[7168];   // ws [64][36] (2304) union pl (7168)
    float*  ws  = smem;
    float4* pl4 = (float4*)smem;
    const int tid    = threadIdx.x;
    const int cog    = tid & 7;
    const int pxg    = (tid >> 3) % 14;
    const int cic    = tid / 112;                 // 0..3
    const int n      = blockIdx.x / 14;
    const int p0     = (blockIdx.x % 14) * 56 + pxg * 4;
    const int cobase = blockIdx.y * 32;

    for (int idx = tid; idx < 2048; idx += 448) {
        int co = idx >> 6, ci = idx & 63;
        ws[ci * 36 + co] = w3[(size_t)(cobase + co) * 64 + ci];
    }
    __syncthreads();

    float4 acc0 = {0,0,0,0}, acc1 = acc0, acc2 = acc0, acc3 = acc0;
    const float* hp = h3 + ((size_t)n * 64 + cic * 16) * 784 + p0;
    const float* wp = ws + (cic * 16) * 36 + cog * 4;
    #pragma unroll 8
    for (int i = 0; i < 16; ++i) {
        float4 u = *(const float4*)(hp + (size_t)i * 784);
        float4 w = *(const float4*)(wp + i * 36);
        acc0.x += fabsf(u.x - w.x); acc0.y += fabsf(u.y - w.x); acc0.z += fabsf(u.z - w.x); acc0.w += fabsf(u.w - w.x);
        acc1.x += fabsf(u.x - w.y); acc1.y += fabsf(u.y - w.y); acc1.z += fabsf(u.z - w.y); acc1.w += fabsf(u.w - w.y);
        acc2.x += fabsf(u.x - w.z); acc2.y += fabsf(u.y - w.z); acc2.z += fabsf(u.z - w.z); acc2.w += fabsf(u.w - w.z);
        acc3.x += fabsf(u.x - w.w); acc3.y += fabsf(u.y - w.w); acc3.z += fabsf(u.z - w.w); acc3.w += fabsf(u.w - w.w);
    }
    __syncthreads();   // ws reads done before pl overwrites
    const int pbase = pxg * 32 + cog * 4;
    pl4[cic * 448 + pbase + 0] = acc0;
    pl4[cic * 448 + pbase + 1] = acc1;
    pl4[cic * 448 + pbase + 2] = acc2;
    pl4[cic * 448 + pbase + 3] = acc3;
    __syncthreads();

    {
        const int j = cic;
        float4 s = pl4[pbase + j];
        #pragma unroll
        for (int c = 1; c < 4; ++c) {
            float4 t = pl4[c * 448 + pbase + j];
            s.x += t.x; s.y += t.y; s.z += t.z; s.w += t.w;
        }
        const int co = cobase + cog * 4 + j;
        float inv = g3[co] * rsqrtf(v3[co] + 1e-5f);
        float bb  = b3[co] - m3[co] * inv;
        size_t obase = ((size_t)n * 256 + co) * 784 + p0;
        float4 r = *(const float4*)(x + obase);
        float4 o;
        o.x = fmaxf(-s.x * inv + bb + r.x, 0.f);
        o.y = fmaxf(-s.y * inv + bb + r.y, 0.f);
        o.z = fmaxf(-s.z * inv + bb + r.z, 0.f);
        o.w = fmaxf(-s.w * inv + bb + r.w, 0.f);
        *(float4*)(out + obase) = o;
    }
}

extern "C" void kernel_launch(void* const* d_in, const int* in_sizes, int n_in,
                              void* d_out, int out_size, void* d_ws, size_t ws_size,
                              hipStream_t stream) {
    const float* x  = (const float*)d_in[0];
    const float* w1 = (const float*)d_in[1];
    const float* wp = (const float*)d_in[2];
    const float* w2 = (const float*)d_in[3];
    const float* w3 = (const float*)d_in[4];
    const float* g1 = (const float*)d_in[5];
    const float* b1 = (const float*)d_in[6];
    const float* m1 = (const float*)d_in[7];
    const float* v1 = (const float*)d_in[8];
    const float* g2 = (const float*)d_in[9];
    const float* b2 = (const float*)d_in[10];
    const float* m2 = (const float*)d_in[11];
    const float* v2 = (const float*)d_in[12];
    const float* g3 = (const float*)d_in[13];
    const float* b3 = (const float*)d_in[14];
    const float* m3 = (const float*)d_in[15];
    const float* v3 = (const float*)d_in[16];
    float* out = (float*)d_out;

    float* wsf = (float*)d_ws;
    float* h2p = wsf;                 // 491520 floats
    float* w2t = wsf + 491520;        // 36864 floats [576 r][64 co]
    float* h3  = wsf + 528384;        // 401408 floats

    ka_fused<<<dim3(16, 2, 8), 448, 0, stream>>>(x, w1, wp, w2,
                                                 g1, b1, m1, v1, h2p, w2t);
    k3_conv<<<dim3(8, 14, 8), 256, 0, stream>>>(h2p, w2t, g2, b2, m2, v2, h3);
    k6_adder1x1_bn_res_relu<<<dim3(112, 8), 448, 0, stream>>>(h3, w3, x, g3, b3, m3, v3, out);
}